// Round 2
// baseline (135.224 us; speedup 1.0000x reference)
//
#include <hip/hip_runtime.h>
#include <hip/hip_bf16.h>
#include <stdint.h>

// out[i][j] = dot(x[i], y[j]) / max(|x[i]|*|y[j]|, 1e-8) / 0.05
// x,y: [4096,1024] f32; out: [4096,4096] f32
#define MDIM 4096
#define NDIM 4096
#define KDIM 1024
#define TEMP_INV 20.0f

#define BM 256
#define BN 128
#define BK 64
#define NT (KDIM / BK)            // 16 K-tiles
#define ABUF_E (BM * BK)          // 16384 elems = 32 KB
#define BBUF_E (BN * BK)          // 8192  elems = 16 KB
#define BUF_E (ABUF_E + BBUF_E)   // 24576 elems = 48 KB per buffer, 3 buffers = 144 KB

typedef __bf16 bf16x8 __attribute__((ext_vector_type(8)));
typedef float f32x16 __attribute__((ext_vector_type(16)));

typedef __attribute__((address_space(3))) void lds_void_t;
typedef __attribute__((address_space(1))) void glb_void_t;

__device__ __forceinline__ void async_copy16(const void* g, void* l) {
    __builtin_amdgcn_global_load_lds((glb_void_t*)(uintptr_t)g,
                                     (lds_void_t*)(uint32_t)(uintptr_t)l,
                                     16, 0, 0);
}

__device__ __forceinline__ unsigned short f32_to_bf16_rne(float f) {
    union { float f; uint32_t u; } v;
    v.f = f;
    uint32_t u = v.u;
    return (unsigned short)((u + 0x7FFFu + ((u >> 16) & 1u)) >> 16);
}

// Wave-per-row prep: no LDS, no __syncthreads. Block = 4 waves = 4 rows.
__global__ __launch_bounds__(256) void prep_kernel(const float* __restrict__ x,
                                                   const float* __restrict__ y,
                                                   unsigned short* __restrict__ xb,
                                                   unsigned short* __restrict__ yb,
                                                   float* __restrict__ rnx,
                                                   float* __restrict__ rny) {
    const int wv = threadIdx.x >> 6;
    const int lane = threadIdx.x & 63;
    const int row = blockIdx.x * 4 + wv;
    const float* src = blockIdx.y ? y : x;
    unsigned short* dst = blockIdx.y ? yb : xb;
    float* rn = blockIdx.y ? rny : rnx;

    const float4* s4 = (const float4*)(src + (size_t)row * KDIM);
    ushort4* d4 = (ushort4*)(dst + (size_t)row * KDIM);

    float ss = 0.0f;
#pragma unroll
    for (int it = 0; it < 4; ++it) {
        float4 v = s4[lane + it * 64];
        ss += v.x * v.x + v.y * v.y + v.z * v.z + v.w * v.w;
        ushort4 b;
        b.x = f32_to_bf16_rne(v.x);
        b.y = f32_to_bf16_rne(v.y);
        b.z = f32_to_bf16_rne(v.z);
        b.w = f32_to_bf16_rne(v.w);
        d4[lane + it * 64] = b;
    }
#pragma unroll
    for (int off = 32; off > 0; off >>= 1) ss += __shfl_down(ss, off);
    if (lane == 0) rn[row] = 1.0f / fmaxf(sqrtf(ss), 1e-8f);
}

// One K-tile step of the pipelined GEMM.
// MODE 0: stage K-tile t+2 into An/Bn, boundary s_waitcnt vmcnt(6) (leave t+2's
//         6 loads in flight across the barrier — T4 counted-vmcnt).
// MODE 1: no staging, boundary vmcnt(0) (second-to-last tile; retire last tile's loads).
// MODE 2: no staging, no boundary sync (last tile; falls through to epilogue).
template <int MODE>
__device__ __forceinline__ void ktile_step(const __bf16* Ac, const __bf16* Bc,
                                           __bf16* An, __bf16* Bn,
                                           const unsigned short* gAsrc,
                                           const unsigned short* gBsrc, int kt2,
                                           int aOff0, int aOff1, int bOff0, int bOff1,
                                           int half, int rsw, int tid,
                                           f32x16& acc00, f32x16& acc01,
                                           f32x16& acc10, f32x16& acc11) {
    // ---- phase A: read a-frags (i=0,1) + b-frags (j=0), stage A segs 0,1 + B seg 0
    bf16x8 a0[4], a1[4], b0[4];
#pragma unroll
    for (int s = 0; s < 4; ++s) {
        const int cp = ((2 * s + half) ^ rsw) * 8;
        a0[s] = *(const bf16x8*)(Ac + aOff0 + cp);
        a1[s] = *(const bf16x8*)(Ac + aOff1 + cp);
        b0[s] = *(const bf16x8*)(Bc + bOff0 + cp);
    }
    if constexpr (MODE == 0) {
        async_copy16(gAsrc + kt2, An + tid * 8);
        async_copy16(gAsrc + kt2 + (size_t)64 * KDIM, An + 4096 + tid * 8);
        async_copy16(gBsrc + kt2, Bn + tid * 8);
    }
    __builtin_amdgcn_s_barrier();
    asm volatile("s_waitcnt lgkmcnt(0)" ::: "memory");
    __builtin_amdgcn_sched_barrier(0);
    __builtin_amdgcn_s_setprio(1);
#pragma unroll
    for (int s = 0; s < 4; ++s)
        acc00 = __builtin_amdgcn_mfma_f32_32x32x16_bf16(a0[s], b0[s], acc00, 0, 0, 0);
#pragma unroll
    for (int s = 0; s < 4; ++s)
        acc10 = __builtin_amdgcn_mfma_f32_32x32x16_bf16(a1[s], b0[s], acc10, 0, 0, 0);
    __builtin_amdgcn_s_setprio(0);
    __builtin_amdgcn_s_barrier();

    // ---- phase B: read b-frags (j=1), stage A segs 2,3 + B seg 1
    bf16x8 b1[4];
#pragma unroll
    for (int s = 0; s < 4; ++s) {
        const int cp = ((2 * s + half) ^ rsw) * 8;
        b1[s] = *(const bf16x8*)(Bc + bOff1 + cp);
    }
    if constexpr (MODE == 0) {
        async_copy16(gAsrc + kt2 + (size_t)128 * KDIM, An + 8192 + tid * 8);
        async_copy16(gAsrc + kt2 + (size_t)192 * KDIM, An + 12288 + tid * 8);
        async_copy16(gBsrc + kt2 + (size_t)64 * KDIM, Bn + 4096 + tid * 8);
    }
    __builtin_amdgcn_s_barrier();
    asm volatile("s_waitcnt lgkmcnt(0)" ::: "memory");
    __builtin_amdgcn_sched_barrier(0);
    __builtin_amdgcn_s_setprio(1);
#pragma unroll
    for (int s = 0; s < 4; ++s)
        acc01 = __builtin_amdgcn_mfma_f32_32x32x16_bf16(a0[s], b1[s], acc01, 0, 0, 0);
#pragma unroll
    for (int s = 0; s < 4; ++s)
        acc11 = __builtin_amdgcn_mfma_f32_32x32x16_bf16(a1[s], b1[s], acc11, 0, 0, 0);
    __builtin_amdgcn_s_setprio(0);
    if constexpr (MODE == 0) {
        // K-tile boundary: retire t+1's 6 loads, keep t+2's 6 in flight.
        asm volatile("s_waitcnt vmcnt(6)" ::: "memory");
        __builtin_amdgcn_sched_barrier(0);
        __builtin_amdgcn_s_barrier();
    } else if constexpr (MODE == 1) {
        asm volatile("s_waitcnt vmcnt(0)" ::: "memory");
        __builtin_amdgcn_sched_barrier(0);
        __builtin_amdgcn_s_barrier();
    }
}

// 256x128 tile, BK=64, 3 LDS buffers, 2-K-tile-ahead prefetch, counted vmcnt(6)
// at K-tile boundaries (loads stay in flight across barriers), setprio around
// MFMA clusters. LDS chunk-XOR swizzle + pre-swizzled global_load_lds source
// carried over unchanged from the verified 128x128 kernel.
__global__ __launch_bounds__(512, 2) void gemm_cos_kernel(const unsigned short* __restrict__ Xb,
                                                          const unsigned short* __restrict__ Yb,
                                                          const float* __restrict__ rnx,
                                                          const float* __restrict__ rny,
                                                          float* __restrict__ out) {
    __shared__ __bf16 lds[3 * BUF_E];  // 144 KB

    const int tid = threadIdx.x;

    // XCD-aware bijective swizzle: nwg = 32*16 = 512, 512 % 8 == 0.
    const int lin = (int)(blockIdx.y * gridDim.x + blockIdx.x);
    const int swz = (lin & 7) * 64 + (lin >> 3);
    const int bm = swz >> 5;   // / (NDIM/BN = 32)
    const int bn = swz & 31;

    // Staging: thread t covers seg-row (t>>3), chunk slot (t&7); fetches global
    // chunk (t&7)^(srow&7) so LDS slot c' holds chunk c'^(row&7).
    const int srow = tid >> 3;
    const int gch = (tid & 7) ^ (srow & 7);
    const unsigned short* gAsrc = Xb + (size_t)(bm * BM + srow) * KDIM + gch * 8;
    const unsigned short* gBsrc = Yb + (size_t)(bn * BN + srow) * KDIM + gch * 8;

    const int lane = tid & 63;
    const int wv = tid >> 6;
    const int wm = wv >> 1;    // 0..3 -> row offset wm*64
    const int wn = wv & 1;     // 0..1 -> col offset wn*64
    const int n32 = lane & 31;
    const int half = lane >> 5;
    const int rsw = n32 & 7;

    const int aOff0 = (wm * 64 + n32) * BK;
    const int aOff1 = (wm * 64 + 32 + n32) * BK;
    const int bOff0 = (wn * 64 + n32) * BK;
    const int bOff1 = (wn * 64 + 32 + n32) * BK;

    f32x16 acc00 = {}, acc01 = {}, acc10 = {}, acc11 = {};

    // ---- prologue: stage K-tile 0 -> buf0, K-tile 1 -> buf1 (12 loads)
#pragma unroll
    for (int seg = 0; seg < 4; ++seg)
        async_copy16(gAsrc + (size_t)(seg * 64) * KDIM, lds + seg * 4096 + tid * 8);
#pragma unroll
    for (int seg = 0; seg < 2; ++seg)
        async_copy16(gBsrc + (size_t)(seg * 64) * KDIM, lds + ABUF_E + seg * 4096 + tid * 8);
#pragma unroll
    for (int seg = 0; seg < 4; ++seg)
        async_copy16(gAsrc + BK + (size_t)(seg * 64) * KDIM, lds + BUF_E + seg * 4096 + tid * 8);
#pragma unroll
    for (int seg = 0; seg < 2; ++seg)
        async_copy16(gBsrc + BK + (size_t)(seg * 64) * KDIM,
                     lds + BUF_E + ABUF_E + seg * 4096 + tid * 8);
    asm volatile("s_waitcnt vmcnt(6)" ::: "memory");  // K-tile 0 ready; tile 1 in flight
    __builtin_amdgcn_sched_barrier(0);
    __builtin_amdgcn_s_barrier();

    // ---- main loop: t = 0..13, staging t+2 into buffer (t+2)%3
    int cur = 0;
#pragma unroll 1
    for (int t = 0; t < NT - 2; ++t) {
        const int nx2 = (cur == 0) ? 2 : cur - 1;  // (t+2)%3
        const __bf16* Ac = lds + cur * BUF_E;
        __bf16* An = lds + nx2 * BUF_E;
        ktile_step<0>(Ac, Ac + ABUF_E, An, An + ABUF_E, gAsrc, gBsrc, (t + 2) * BK,
                      aOff0, aOff1, bOff0, bOff1, half, rsw, tid,
                      acc00, acc01, acc10, acc11);
        cur = (cur == 2) ? 0 : cur + 1;
    }
    // t = 14 (buf 2): retire tile 15's loads at the boundary
    {
        const __bf16* Ac = lds + 2 * BUF_E;
        ktile_step<1>(Ac, Ac + ABUF_E, lds, lds, gAsrc, gBsrc, 0,
                      aOff0, aOff1, bOff0, bOff1, half, rsw, tid,
                      acc00, acc01, acc10, acc11);
    }
    // t = 15 (buf 0): last tile, fall through to epilogue
    {
        const __bf16* Ac = lds;
        ktile_step<2>(Ac, Ac + ABUF_E, lds, lds, gAsrc, gBsrc, 0,
                      aOff0, aOff1, bOff0, bOff1, half, rsw, tid,
                      acc00, acc01, acc10, acc11);
    }

    // C/D layout (measured m74/m101): col = lane&31, row = (reg&3) + 8*(reg>>2) + 4*(lane>>5).
    const int grb = bm * BM + wm * 64 + 4 * half;
    const int gcb = bn * BN + wn * 64 + n32;
    const float sy0 = rny[gcb] * TEMP_INV;
    const float sy1 = rny[gcb + 32] * TEMP_INV;

#pragma unroll
    for (int r = 0; r < 16; ++r) {
        const int ro = (r & 3) + 8 * (r >> 2);
        {
            const int grow = grb + ro;
            const float rx = rnx[grow];
            out[(size_t)grow * NDIM + gcb] = acc00[r] * rx * sy0;
            out[(size_t)grow * NDIM + gcb + 32] = acc01[r] * rx * sy1;
        }
        {
            const int grow = grb + 32 + ro;
            const float rx = rnx[grow];
            out[(size_t)grow * NDIM + gcb] = acc10[r] * rx * sy0;
            out[(size_t)grow * NDIM + gcb + 32] = acc11[r] * rx * sy1;
        }
    }
}

extern "C" void kernel_launch(void* const* d_in, const int* in_sizes, int n_in,
                              void* d_out, int out_size, void* d_ws, size_t ws_size,
                              hipStream_t stream) {
    const float* x = (const float*)d_in[0];
    const float* y = (const float*)d_in[1];
    float* out = (float*)d_out;

    char* ws = (char*)d_ws;
    unsigned short* Xb = (unsigned short*)ws;                              // 8 MB
    unsigned short* Yb = (unsigned short*)(ws + (size_t)MDIM * KDIM * 2);  // 8 MB
    float* rnx = (float*)(ws + (size_t)(MDIM + NDIM) * KDIM * 2);
    float* rny = rnx + MDIM;

    prep_kernel<<<dim3(MDIM / 4, 2), 256, 0, stream>>>(x, y, Xb, Yb, rnx, rny);
    gemm_cos_kernel<<<dim3(NDIM / BN, MDIM / BM), 512, 0, stream>>>(Xb, Yb, rnx, rny, out);
}

// Round 3
// 127.727 us; speedup vs baseline: 1.0587x; 1.0587x over previous
//
#include <hip/hip_runtime.h>
#include <hip/hip_bf16.h>
#include <stdint.h>

// out[i][j] = dot(x[i], y[j]) / max(|x[i]|*|y[j]|, 1e-8) / 0.05
// x,y: [4096,1024] f32; out: [4096,4096] f32
#define MDIM 4096
#define NDIM 4096
#define KDIM 1024
#define TEMP_INV 20.0f

#define BM 256
#define BN 256
#define BK 64
#define NT (KDIM / BK)       // 16 K-tiles
#define ABUF_E (BM * BK)     // 16384 elems = 32 KB (A region)
#define BUF_E (2 * ABUF_E)   // 32768 elems = 64 KB per buffer; 2 buffers = 128 KB

typedef __bf16 bf16x8 __attribute__((ext_vector_type(8)));
typedef float f32x16 __attribute__((ext_vector_type(16)));

typedef __attribute__((address_space(3))) void lds_void_t;
typedef __attribute__((address_space(1))) void glb_void_t;

__device__ __forceinline__ void async_copy16(const void* g, void* l) {
    __builtin_amdgcn_global_load_lds((glb_void_t*)(uintptr_t)g,
                                     (lds_void_t*)(uint32_t)(uintptr_t)l,
                                     16, 0, 0);
}

__device__ __forceinline__ unsigned short f32_to_bf16_rne(float f) {
    union { float f; uint32_t u; } v;
    v.f = f;
    uint32_t u = v.u;
    return (unsigned short)((u + 0x7FFFu + ((u >> 16) & 1u)) >> 16);
}

// Wave-per-row prep: no LDS, no __syncthreads. Block = 4 waves = 4 rows.
__global__ __launch_bounds__(256) void prep_kernel(const float* __restrict__ x,
                                                   const float* __restrict__ y,
                                                   unsigned short* __restrict__ xb,
                                                   unsigned short* __restrict__ yb,
                                                   float* __restrict__ rnx,
                                                   float* __restrict__ rny) {
    const int wv = threadIdx.x >> 6;
    const int lane = threadIdx.x & 63;
    const int row = blockIdx.x * 4 + wv;
    const float* src = blockIdx.y ? y : x;
    unsigned short* dst = blockIdx.y ? yb : xb;
    float* rn = blockIdx.y ? rny : rnx;

    const float4* s4 = (const float4*)(src + (size_t)row * KDIM);
    ushort4* d4 = (ushort4*)(dst + (size_t)row * KDIM);

    float ss = 0.0f;
#pragma unroll
    for (int it = 0; it < 4; ++it) {
        float4 v = s4[lane + it * 64];
        ss += v.x * v.x + v.y * v.y + v.z * v.z + v.w * v.w;
        ushort4 b;
        b.x = f32_to_bf16_rne(v.x);
        b.y = f32_to_bf16_rne(v.y);
        b.z = f32_to_bf16_rne(v.z);
        b.w = f32_to_bf16_rne(v.w);
        d4[lane + it * 64] = b;
    }
#pragma unroll
    for (int off = 32; off > 0; off >>= 1) ss += __shfl_down(ss, off);
    if (lane == 0) rn[row] = 1.0f / fmaxf(sqrtf(ss), 1e-8f);
}

// One K-tile = 4 quadrant-phases. Wave tile 128x64 (2 qm x 2 qn quadrants of
// 64x32; each quadrant = 2 row-groups x 1 col-group x 4 k-slices = 8 MFMA).
// Staging for K-tile t+2 goes into THIS buffer (same parity), region-by-region
// after the region's last read has retired:
//   B region free after ph1-end barrier  -> B-stage issued in ph2
//   A region free after ph2-end barrier  -> A-stage issued in ph3
// Boundary: vmcnt(8) retires t+1's 8 loads, leaves t+2's 8 in flight (T4).
// MODE 0: stage + vmcnt(8).  MODE 1: no stage, vmcnt(0).  MODE 2: no stage, no wait.
template <int MODE>
__device__ __forceinline__ void ktile_step(const __bf16* __restrict__ buf,
                                           __bf16* __restrict__ bufw,
                                           const unsigned short* gA,
                                           const unsigned short* gB, int kt2,
                                           int aB0, int aB1, int aB2, int aB3,
                                           int bB0, int bB1,
                                           int half, int rsw, int tid,
                                           f32x16& acc00, f32x16& acc01,
                                           f32x16& acc10, f32x16& acc11,
                                           f32x16& acc20, f32x16& acc21,
                                           f32x16& acc30, f32x16& acc31) {
    bf16x8 a[8], b0[4], b1[4];

    // ---- ph0: read A row-groups 0,1 + B col-group 0; MFMA quadrant (qm0,qn0)
#pragma unroll
    for (int s = 0; s < 4; ++s) {
        const int cp = ((2 * s + half) ^ rsw) * 8;
        a[s] = *(const bf16x8*)(buf + aB0 + cp);
        a[4 + s] = *(const bf16x8*)(buf + aB1 + cp);
        b0[s] = *(const bf16x8*)(buf + bB0 + cp);
    }
    __builtin_amdgcn_s_barrier();
    asm volatile("s_waitcnt lgkmcnt(0)" ::: "memory");
    __builtin_amdgcn_sched_barrier(0);
    __builtin_amdgcn_s_setprio(1);
#pragma unroll
    for (int s = 0; s < 4; ++s)
        acc00 = __builtin_amdgcn_mfma_f32_32x32x16_bf16(a[s], b0[s], acc00, 0, 0, 0);
#pragma unroll
    for (int s = 0; s < 4; ++s)
        acc10 = __builtin_amdgcn_mfma_f32_32x32x16_bf16(a[4 + s], b0[s], acc10, 0, 0, 0);
    __builtin_amdgcn_s_setprio(0);
    __builtin_amdgcn_s_barrier();

    // ---- ph1: read B col-group 1; MFMA quadrant (qm0,qn1)
#pragma unroll
    for (int s = 0; s < 4; ++s) {
        const int cp = ((2 * s + half) ^ rsw) * 8;
        b1[s] = *(const bf16x8*)(buf + bB1 + cp);
    }
    __builtin_amdgcn_s_barrier();
    asm volatile("s_waitcnt lgkmcnt(0)" ::: "memory");
    __builtin_amdgcn_sched_barrier(0);
    __builtin_amdgcn_s_setprio(1);
#pragma unroll
    for (int s = 0; s < 4; ++s)
        acc01 = __builtin_amdgcn_mfma_f32_32x32x16_bf16(a[s], b1[s], acc01, 0, 0, 0);
#pragma unroll
    for (int s = 0; s < 4; ++s)
        acc11 = __builtin_amdgcn_mfma_f32_32x32x16_bf16(a[4 + s], b1[s], acc11, 0, 0, 0);
    __builtin_amdgcn_s_setprio(0);
    __builtin_amdgcn_s_barrier();

    // ---- ph2: re-read A row-groups 2,3; issue B-stage(t+2); MFMA (qm1,qn0)
#pragma unroll
    for (int s = 0; s < 4; ++s) {
        const int cp = ((2 * s + half) ^ rsw) * 8;
        a[s] = *(const bf16x8*)(buf + aB2 + cp);
        a[4 + s] = *(const bf16x8*)(buf + aB3 + cp);
    }
    if constexpr (MODE == 0) {
#pragma unroll
        for (int seg = 0; seg < 4; ++seg)
            async_copy16(gB + kt2 + (size_t)(seg * 64) * KDIM,
                         bufw + ABUF_E + seg * 4096 + tid * 8);
    }
    __builtin_amdgcn_s_barrier();
    asm volatile("s_waitcnt lgkmcnt(0)" ::: "memory");
    __builtin_amdgcn_sched_barrier(0);
    __builtin_amdgcn_s_setprio(1);
#pragma unroll
    for (int s = 0; s < 4; ++s)
        acc20 = __builtin_amdgcn_mfma_f32_32x32x16_bf16(a[s], b0[s], acc20, 0, 0, 0);
#pragma unroll
    for (int s = 0; s < 4; ++s)
        acc30 = __builtin_amdgcn_mfma_f32_32x32x16_bf16(a[4 + s], b0[s], acc30, 0, 0, 0);
    __builtin_amdgcn_s_setprio(0);
    __builtin_amdgcn_s_barrier();

    // ---- ph3: issue A-stage(t+2); MFMA (qm1,qn1) from regs; boundary wait
    if constexpr (MODE == 0) {
#pragma unroll
        for (int seg = 0; seg < 4; ++seg)
            async_copy16(gA + kt2 + (size_t)(seg * 64) * KDIM,
                         bufw + seg * 4096 + tid * 8);
    }
    __builtin_amdgcn_s_setprio(1);
#pragma unroll
    for (int s = 0; s < 4; ++s)
        acc21 = __builtin_amdgcn_mfma_f32_32x32x16_bf16(a[s], b1[s], acc21, 0, 0, 0);
#pragma unroll
    for (int s = 0; s < 4; ++s)
        acc31 = __builtin_amdgcn_mfma_f32_32x32x16_bf16(a[4 + s], b1[s], acc31, 0, 0, 0);
    __builtin_amdgcn_s_setprio(0);
    if constexpr (MODE == 0) {
        asm volatile("s_waitcnt vmcnt(8)" ::: "memory");  // retire t+1's 8; t+2's stay in flight
        __builtin_amdgcn_sched_barrier(0);
        __builtin_amdgcn_s_barrier();
    } else if constexpr (MODE == 1) {
        asm volatile("s_waitcnt vmcnt(0)" ::: "memory");  // retire last tile's 8
        __builtin_amdgcn_sched_barrier(0);
        __builtin_amdgcn_s_barrier();
    }
}

// 256x256 tile, BK=64, 512 threads / 8 waves (2M x 4N), wave tile 128x64,
// 2 LDS buffers (128 KB), staging 1.5 K-tiles ahead, counted vmcnt(8) at
// K-tile boundaries. Chunk-XOR LDS swizzle + pre-swizzled global source
// carried over unchanged (verified layout).
__global__ __launch_bounds__(512, 2) void gemm_cos_kernel(const unsigned short* __restrict__ Xb,
                                                          const unsigned short* __restrict__ Yb,
                                                          const float* __restrict__ rnx,
                                                          const float* __restrict__ rny,
                                                          float* __restrict__ out) {
    __shared__ __bf16 lds[2 * BUF_E];  // 128 KB

    const int tid = threadIdx.x;

    // XCD-aware bijective swizzle: nwg = 16*16 = 256, 256 % 8 == 0.
    const int lin = (int)(blockIdx.y * gridDim.x + blockIdx.x);
    const int swz = (lin & 7) * 32 + (lin >> 3);
    const int bm = swz >> 4;
    const int bn = swz & 15;

    // Staging: thread t covers seg-row (t>>3) (0..63), chunk slot (t&7);
    // fetches global chunk (t&7)^(srow&7) so LDS slot c' holds chunk c'^(row&7).
    const int srow = tid >> 3;
    const int gch = (tid & 7) ^ (srow & 7);
    const unsigned short* gAsrc = Xb + (size_t)(bm * BM + srow) * KDIM + gch * 8;
    const unsigned short* gBsrc = Yb + (size_t)(bn * BN + srow) * KDIM + gch * 8;

    const int lane = tid & 63;
    const int wv = tid >> 6;
    const int wm = wv >> 2;   // 0..1 -> A rows wm*128..
    const int wn = wv & 3;    // 0..3 -> B rows wn*64..
    const int n32 = lane & 31;
    const int half = lane >> 5;
    const int rsw = n32 & 7;

    // A row-group bases (4 groups of 32 rows within the wave's 128 rows).
    const int aB0 = (wm * 128 + 0 * 32 + n32) * BK;
    const int aB1 = (wm * 128 + 1 * 32 + n32) * BK;
    const int aB2 = (wm * 128 + 2 * 32 + n32) * BK;
    const int aB3 = (wm * 128 + 3 * 32 + n32) * BK;
    // B col-group bases (2 groups of 32 within the wave's 64 cols).
    const int bB0 = ABUF_E + (wn * 64 + 0 * 32 + n32) * BK;
    const int bB1 = ABUF_E + (wn * 64 + 1 * 32 + n32) * BK;

    f32x16 acc00 = {}, acc01 = {}, acc10 = {}, acc11 = {};
    f32x16 acc20 = {}, acc21 = {}, acc30 = {}, acc31 = {};

    __bf16* buf0 = lds;
    __bf16* buf1 = lds + BUF_E;

    // ---- prologue: stage tile 0 -> buf0 (8 loads), tile 1 -> buf1 (8 loads)
#pragma unroll
    for (int seg = 0; seg < 4; ++seg) {
        async_copy16(gAsrc + (size_t)(seg * 64) * KDIM, buf0 + seg * 4096 + tid * 8);
    }
#pragma unroll
    for (int seg = 0; seg < 4; ++seg) {
        async_copy16(gBsrc + (size_t)(seg * 64) * KDIM, buf0 + ABUF_E + seg * 4096 + tid * 8);
    }
#pragma unroll
    for (int seg = 0; seg < 4; ++seg) {
        async_copy16(gAsrc + BK + (size_t)(seg * 64) * KDIM, buf1 + seg * 4096 + tid * 8);
    }
#pragma unroll
    for (int seg = 0; seg < 4; ++seg) {
        async_copy16(gBsrc + BK + (size_t)(seg * 64) * KDIM, buf1 + ABUF_E + seg * 4096 + tid * 8);
    }
    asm volatile("s_waitcnt vmcnt(8)" ::: "memory");  // tile 0 landed; tile 1 in flight
    __builtin_amdgcn_sched_barrier(0);
    __builtin_amdgcn_s_barrier();

    // ---- main loop: tiles 0..13 stage t+2 into the same-parity buffer
#pragma unroll 1
    for (int t = 0; t < NT - 2; t += 2) {
        ktile_step<0>(buf0, buf0, gAsrc, gBsrc, (t + 2) * BK,
                      aB0, aB1, aB2, aB3, bB0, bB1, half, rsw, tid,
                      acc00, acc01, acc10, acc11, acc20, acc21, acc30, acc31);
        ktile_step<0>(buf1, buf1, gAsrc, gBsrc, (t + 3) * BK,
                      aB0, aB1, aB2, aB3, bB0, bB1, half, rsw, tid,
                      acc00, acc01, acc10, acc11, acc20, acc21, acc30, acc31);
    }
    // tile 14 (buf0): no staging, drain tile 15's loads at boundary
    ktile_step<1>(buf0, buf0, gAsrc, gBsrc, 0,
                  aB0, aB1, aB2, aB3, bB0, bB1, half, rsw, tid,
                  acc00, acc01, acc10, acc11, acc20, acc21, acc30, acc31);
    // tile 15 (buf1): pure compute, falls through to epilogue
    ktile_step<2>(buf1, buf1, gAsrc, gBsrc, 0,
                  aB0, aB1, aB2, aB3, bB0, bB1, half, rsw, tid,
                  acc00, acc01, acc10, acc11, acc20, acc21, acc30, acc31);

    // C/D layout (measured m74/m101): col = lane&31, row = (reg&3) + 8*(reg>>2) + 4*(lane>>5).
    const int grb = bm * BM + wm * 128 + 4 * half;
    const int gcb = bn * BN + wn * 64 + n32;
    const float sy0 = rny[gcb] * TEMP_INV;
    const float sy1 = rny[gcb + 32] * TEMP_INV;

#define STORE_G(accL, accR, goff)                                          \
    {                                                                      \
        _Pragma("unroll") for (int r = 0; r < 16; ++r) {                   \
            const int ro = (r & 3) + 8 * (r >> 2);                         \
            const int grow = grb + (goff) + ro;                            \
            const float rx = rnx[grow];                                    \
            out[(size_t)grow * NDIM + gcb] = accL[r] * rx * sy0;           \
            out[(size_t)grow * NDIM + gcb + 32] = accR[r] * rx * sy1;      \
        }                                                                  \
    }

    STORE_G(acc00, acc01, 0)
    STORE_G(acc10, acc11, 32)
    STORE_G(acc20, acc21, 64)
    STORE_G(acc30, acc31, 96)
#undef STORE_G
}

extern "C" void kernel_launch(void* const* d_in, const int* in_sizes, int n_in,
                              void* d_out, int out_size, void* d_ws, size_t ws_size,
                              hipStream_t stream) {
    const float* x = (const float*)d_in[0];
    const float* y = (const float*)d_in[1];
    float* out = (float*)d_out;

    char* ws = (char*)d_ws;
    unsigned short* Xb = (unsigned short*)ws;                              // 8 MB
    unsigned short* Yb = (unsigned short*)(ws + (size_t)MDIM * KDIM * 2);  // 8 MB
    float* rnx = (float*)(ws + (size_t)(MDIM + NDIM) * KDIM * 2);
    float* rny = rnx + MDIM;

    prep_kernel<<<dim3(MDIM / 4, 2), 256, 0, stream>>>(x, y, Xb, Yb, rnx, rny);
    gemm_cos_kernel<<<dim3(NDIM / BN, MDIM / BM), 512, 0, stream>>>(Xb, Yb, rnx, rny, out);
}

// Round 4
// 126.449 us; speedup vs baseline: 1.0694x; 1.0101x over previous
//
#include <hip/hip_runtime.h>
#include <hip/hip_bf16.h>
#include <stdint.h>

// out[i][j] = dot(x[i], y[j]) / max(|x[i]|*|y[j]|, 1e-8) / 0.05
// x,y: [4096,1024] f32; out: [4096,4096] f32
#define MDIM 4096
#define NDIM 4096
#define KDIM 1024
#define TEMP_INV 20.0f

#define BM 256
#define BN 256
#define BK 64
#define NT (KDIM / BK)       // 16 K-tiles
#define ABUF_E (BM * BK)     // 16384 elems = 32 KB (A region)
#define BUF_E (2 * ABUF_E)   // 32768 elems = 64 KB per buffer; 2 buffers = 128 KB

typedef __bf16 bf16x8 __attribute__((ext_vector_type(8)));
typedef float f32x16 __attribute__((ext_vector_type(16)));

typedef __attribute__((address_space(3))) void lds_void_t;
typedef __attribute__((address_space(1))) void glb_void_t;

__device__ __forceinline__ void async_copy16(const void* g, void* l) {
    __builtin_amdgcn_global_load_lds((glb_void_t*)(uintptr_t)g,
                                     (lds_void_t*)(uint32_t)(uintptr_t)l,
                                     16, 0, 0);
}

__device__ __forceinline__ unsigned short f32_to_bf16_rne(float f) {
    union { float f; uint32_t u; } v;
    v.f = f;
    uint32_t u = v.u;
    return (unsigned short)((u + 0x7FFFu + ((u >> 16) & 1u)) >> 16);
}

// Wave-per-row prep: no LDS, no __syncthreads. Block = 4 waves = 4 rows.
__global__ __launch_bounds__(256) void prep_kernel(const float* __restrict__ x,
                                                   const float* __restrict__ y,
                                                   unsigned short* __restrict__ xb,
                                                   unsigned short* __restrict__ yb,
                                                   float* __restrict__ rnx,
                                                   float* __restrict__ rny) {
    const int wv = threadIdx.x >> 6;
    const int lane = threadIdx.x & 63;
    const int row = blockIdx.x * 4 + wv;
    const float* src = blockIdx.y ? y : x;
    unsigned short* dst = blockIdx.y ? yb : xb;
    float* rn = blockIdx.y ? rny : rnx;

    const float4* s4 = (const float4*)(src + (size_t)row * KDIM);
    ushort4* d4 = (ushort4*)(dst + (size_t)row * KDIM);

    float ss = 0.0f;
#pragma unroll
    for (int it = 0; it < 4; ++it) {
        float4 v = s4[lane + it * 64];
        ss += v.x * v.x + v.y * v.y + v.z * v.z + v.w * v.w;
        ushort4 b;
        b.x = f32_to_bf16_rne(v.x);
        b.y = f32_to_bf16_rne(v.y);
        b.z = f32_to_bf16_rne(v.z);
        b.w = f32_to_bf16_rne(v.w);
        d4[lane + it * 64] = b;
    }
#pragma unroll
    for (int off = 32; off > 0; off >>= 1) ss += __shfl_down(ss, off);
    if (lane == 0) rn[row] = 1.0f / fmaxf(sqrtf(ss), 1e-8f);
}

// One K-tile: issue next-tile staging FIRST (8 global_load_lds get the whole
// tile's compute time to land), then 24 ds_reads + 32 MFMA straight-line with
// NO intra-tile barriers (reads hit the stable current buffer; stage writes go
// to the other buffer -> no cross-wave hazard). Tile ends with vmcnt(0) (free:
// loads are a full tile old) + ONE s_barrier. Waves drift within the tile, so
// one wave's LDS bursts overlap another's MFMA (m114), and the compiler's
// counted lgkmcnt pipelines reads under MFMAs within a wave.
template <bool STAGE>
__device__ __forceinline__ void ktile(const __bf16* __restrict__ buf,
                                      __bf16* __restrict__ nbuf,
                                      const unsigned short* gA,
                                      const unsigned short* gB, int ktn,
                                      int aB0, int aB1, int aB2, int aB3,
                                      int bB0, int bB1,
                                      int half, int rsw, int tid,
                                      f32x16& acc00, f32x16& acc01,
                                      f32x16& acc10, f32x16& acc11,
                                      f32x16& acc20, f32x16& acc21,
                                      f32x16& acc30, f32x16& acc31) {
    if constexpr (STAGE) {
#pragma unroll
        for (int seg = 0; seg < 4; ++seg)
            async_copy16(gA + ktn + (size_t)(seg * 64) * KDIM, nbuf + seg * 4096 + tid * 8);
#pragma unroll
        for (int seg = 0; seg < 4; ++seg)
            async_copy16(gB + ktn + (size_t)(seg * 64) * KDIM,
                         nbuf + ABUF_E + seg * 4096 + tid * 8);
    }

    bf16x8 a[8], b0[4], b1[4];
#pragma unroll
    for (int s = 0; s < 4; ++s) {
        const int cp = ((2 * s + half) ^ rsw) * 8;
        a[s] = *(const bf16x8*)(buf + aB0 + cp);
        a[4 + s] = *(const bf16x8*)(buf + aB1 + cp);
        b0[s] = *(const bf16x8*)(buf + bB0 + cp);
    }
    __builtin_amdgcn_s_setprio(1);
#pragma unroll
    for (int s = 0; s < 4; ++s)
        acc00 = __builtin_amdgcn_mfma_f32_32x32x16_bf16(a[s], b0[s], acc00, 0, 0, 0);
#pragma unroll
    for (int s = 0; s < 4; ++s)
        acc10 = __builtin_amdgcn_mfma_f32_32x32x16_bf16(a[4 + s], b0[s], acc10, 0, 0, 0);
    __builtin_amdgcn_s_setprio(0);

#pragma unroll
    for (int s = 0; s < 4; ++s) {
        const int cp = ((2 * s + half) ^ rsw) * 8;
        b1[s] = *(const bf16x8*)(buf + bB1 + cp);
    }
    __builtin_amdgcn_s_setprio(1);
#pragma unroll
    for (int s = 0; s < 4; ++s)
        acc01 = __builtin_amdgcn_mfma_f32_32x32x16_bf16(a[s], b1[s], acc01, 0, 0, 0);
#pragma unroll
    for (int s = 0; s < 4; ++s)
        acc11 = __builtin_amdgcn_mfma_f32_32x32x16_bf16(a[4 + s], b1[s], acc11, 0, 0, 0);
    __builtin_amdgcn_s_setprio(0);

#pragma unroll
    for (int s = 0; s < 4; ++s) {
        const int cp = ((2 * s + half) ^ rsw) * 8;
        a[s] = *(const bf16x8*)(buf + aB2 + cp);
        a[4 + s] = *(const bf16x8*)(buf + aB3 + cp);
    }
    __builtin_amdgcn_s_setprio(1);
#pragma unroll
    for (int s = 0; s < 4; ++s)
        acc20 = __builtin_amdgcn_mfma_f32_32x32x16_bf16(a[s], b0[s], acc20, 0, 0, 0);
#pragma unroll
    for (int s = 0; s < 4; ++s)
        acc30 = __builtin_amdgcn_mfma_f32_32x32x16_bf16(a[4 + s], b0[s], acc30, 0, 0, 0);
#pragma unroll
    for (int s = 0; s < 4; ++s)
        acc21 = __builtin_amdgcn_mfma_f32_32x32x16_bf16(a[s], b1[s], acc21, 0, 0, 0);
#pragma unroll
    for (int s = 0; s < 4; ++s)
        acc31 = __builtin_amdgcn_mfma_f32_32x32x16_bf16(a[4 + s], b1[s], acc31, 0, 0, 0);
    __builtin_amdgcn_s_setprio(0);

    // Tile boundary: own ds_reads already retired (consumed by MFMAs above);
    // drain staging (a full tile old -> ~free), then the single rendezvous.
    asm volatile("s_waitcnt vmcnt(0)" ::: "memory");
    __builtin_amdgcn_sched_barrier(0);
    __builtin_amdgcn_s_barrier();
}

// 256x256 tile, BK=64, 512 threads / 8 waves (2M x 4N), wave tile 128x64,
// 2 LDS buffers (128 KB), ONE barrier per K-tile. Chunk-XOR LDS swizzle +
// pre-swizzled global_load_lds source carried over unchanged (verified).
__global__ __launch_bounds__(512, 2) void gemm_cos_kernel(const unsigned short* __restrict__ Xb,
                                                          const unsigned short* __restrict__ Yb,
                                                          const float* __restrict__ rnx,
                                                          const float* __restrict__ rny,
                                                          float* __restrict__ out) {
    __shared__ __bf16 lds[2 * BUF_E];  // 128 KB

    const int tid = threadIdx.x;

    // XCD-aware bijective swizzle: nwg = 16*16 = 256, 256 % 8 == 0.
    const int lin = (int)(blockIdx.y * gridDim.x + blockIdx.x);
    const int swz = (lin & 7) * 32 + (lin >> 3);
    const int bm = swz >> 4;
    const int bn = swz & 15;

    // Staging: thread t covers seg-row (t>>3) (0..63), chunk slot (t&7);
    // fetches global chunk (t&7)^(srow&7) so LDS slot c' holds chunk c'^(row&7).
    const int srow = tid >> 3;
    const int gch = (tid & 7) ^ (srow & 7);
    const unsigned short* gAsrc = Xb + (size_t)(bm * BM + srow) * KDIM + gch * 8;
    const unsigned short* gBsrc = Yb + (size_t)(bn * BN + srow) * KDIM + gch * 8;

    const int lane = tid & 63;
    const int wv = tid >> 6;
    const int wm = wv >> 2;   // 0..1 -> A rows wm*128..
    const int wn = wv & 3;    // 0..3 -> B rows wn*64..
    const int n32 = lane & 31;
    const int half = lane >> 5;
    const int rsw = n32 & 7;

    // A row-group bases (4 groups of 32 rows within the wave's 128 rows).
    const int aB0 = (wm * 128 + 0 * 32 + n32) * BK;
    const int aB1 = (wm * 128 + 1 * 32 + n32) * BK;
    const int aB2 = (wm * 128 + 2 * 32 + n32) * BK;
    const int aB3 = (wm * 128 + 3 * 32 + n32) * BK;
    // B col-group bases (2 groups of 32 within the wave's 64 cols).
    const int bB0 = ABUF_E + (wn * 64 + 0 * 32 + n32) * BK;
    const int bB1 = ABUF_E + (wn * 64 + 1 * 32 + n32) * BK;

    f32x16 acc00 = {}, acc01 = {}, acc10 = {}, acc11 = {};
    f32x16 acc20 = {}, acc21 = {}, acc30 = {}, acc31 = {};

    __bf16* buf0 = lds;
    __bf16* buf1 = lds + BUF_E;

    // ---- prologue: stage tile 0 -> buf0 (8 loads), wait, rendezvous
#pragma unroll
    for (int seg = 0; seg < 4; ++seg)
        async_copy16(gAsrc + (size_t)(seg * 64) * KDIM, buf0 + seg * 4096 + tid * 8);
#pragma unroll
    for (int seg = 0; seg < 4; ++seg)
        async_copy16(gBsrc + (size_t)(seg * 64) * KDIM, buf0 + ABUF_E + seg * 4096 + tid * 8);
    asm volatile("s_waitcnt vmcnt(0)" ::: "memory");
    __builtin_amdgcn_sched_barrier(0);
    __builtin_amdgcn_s_barrier();

    // ---- main loop: tiles 0..13 in ping-pong pairs, staging t+1 each tile
#pragma unroll 1
    for (int t = 0; t < NT - 2; t += 2) {
        ktile<true>(buf0, buf1, gAsrc, gBsrc, (t + 1) * BK,
                    aB0, aB1, aB2, aB3, bB0, bB1, half, rsw, tid,
                    acc00, acc01, acc10, acc11, acc20, acc21, acc30, acc31);
        ktile<true>(buf1, buf0, gAsrc, gBsrc, (t + 2) * BK,
                    aB0, aB1, aB2, aB3, bB0, bB1, half, rsw, tid,
                    acc00, acc01, acc10, acc11, acc20, acc21, acc30, acc31);
    }
    // tile 14 (buf0): stage tile 15 -> buf1
    ktile<true>(buf0, buf1, gAsrc, gBsrc, 15 * BK,
                aB0, aB1, aB2, aB3, bB0, bB1, half, rsw, tid,
                acc00, acc01, acc10, acc11, acc20, acc21, acc30, acc31);
    // tile 15 (buf1): no staging
    ktile<false>(buf1, buf0, gAsrc, gBsrc, 0,
                 aB0, aB1, aB2, aB3, bB0, bB1, half, rsw, tid,
                 acc00, acc01, acc10, acc11, acc20, acc21, acc30, acc31);

    // C/D layout (measured m74/m101): col = lane&31, row = (reg&3) + 8*(reg>>2) + 4*(lane>>5).
    const int grb = bm * BM + wm * 128 + 4 * half;
    const int gcb = bn * BN + wn * 64 + n32;
    const float sy0 = rny[gcb] * TEMP_INV;
    const float sy1 = rny[gcb + 32] * TEMP_INV;

#define STORE_G(accL, accR, goff)                                          \
    {                                                                      \
        _Pragma("unroll") for (int r = 0; r < 16; ++r) {                   \
            const int ro = (r & 3) + 8 * (r >> 2);                         \
            const int grow = grb + (goff) + ro;                            \
            const float rx = rnx[grow];                                    \
            out[(size_t)grow * NDIM + gcb] = accL[r] * rx * sy0;           \
            out[(size_t)grow * NDIM + gcb + 32] = accR[r] * rx * sy1;      \
        }                                                                  \
    }

    STORE_G(acc00, acc01, 0)
    STORE_G(acc10, acc11, 32)
    STORE_G(acc20, acc21, 64)
    STORE_G(acc30, acc31, 96)
#undef STORE_G
}

extern "C" void kernel_launch(void* const* d_in, const int* in_sizes, int n_in,
                              void* d_out, int out_size, void* d_ws, size_t ws_size,
                              hipStream_t stream) {
    const float* x = (const float*)d_in[0];
    const float* y = (const float*)d_in[1];
    float* out = (float*)d_out;

    char* ws = (char*)d_ws;
    unsigned short* Xb = (unsigned short*)ws;                              // 8 MB
    unsigned short* Yb = (unsigned short*)(ws + (size_t)MDIM * KDIM * 2);  // 8 MB
    float* rnx = (float*)(ws + (size_t)(MDIM + NDIM) * KDIM * 2);
    float* rny = rnx + MDIM;

    prep_kernel<<<dim3(MDIM / 4, 2), 256, 0, stream>>>(x, y, Xb, Yb, rnx, rny);
    gemm_cos_kernel<<<dim3(NDIM / BN, MDIM / BM), 512, 0, stream>>>(Xb, Yb, rnx, rny, out);
}